// Round 2
// baseline (361.102 us; speedup 1.0000x reference)
//
#include <hip/hip_runtime.h>

// TextCNN: B=128, S=512, E=300, H=64, k_i = i/2+2 in [2,33].
// Virtual-im2col bf16 MFMA GEMM, fused gather, E-split LDS staging.
//   Grid: 128 b x 6 t-slices (96 rows each) = 768 blocks = 3/CU resident.
//   Block: 4 waves, 4-way j(K)-split: each wave owns ALL 6 M-tiles x all
//   active filter groups for its j-range (A-frag LDS-read once/block -> up to
//   4 MFMAs; B-frag comes from global/L2, read once/block -> 6 MFMAs).
//   j-segments balanced to 630 MFMA/wave/half.
//   REGISTER DISCIPLINE (r1 spilled acc to scratch: VGPR 84, WRITE_SIZE 202MB):
//   per (j,u): load B-frags first (<=16 regs), then stream ONE a-frag through
//   its 4 MFMAs (t-loop carries the load). launch_bounds(256,2) so the
//   allocator is never forced below its natural ~140 regs (no spill; LDS
//   still caps residency at 3 blocks/CU).
//   Epilogue: cross-wave j-partial sum via LDS atomicAdd (reuses At), tanh+max.
//   LDS: 128 rows x 168-elem half-rows = 42 KB.
// ws layout: [0, 860KB) wsB bf16 | [1MB, +192KB) wsF f32 (128*64*6).

#define SS     512
#define EE     300
#define HH     64
#define KMAXW  33
#define LP     168          // LDS half-row pitch in elems (336 B)
#define HALFSZ 215040       // wsB elems per E-half (420 steps * 512)
#define RP     68           // epilogue reduce pitch (floats)

typedef __attribute__((ext_vector_type(8))) short bf16x8;
typedef __attribute__((ext_vector_type(4))) float f32x4;

__device__ __forceinline__ unsigned short f2bf(float f) {
    unsigned u = __float_as_uint(f);
    unsigned r = ((u >> 16) & 1u) + 0x7FFFu;   // round-to-nearest-even
    return (unsigned short)((u + r) >> 16);
}

// ---- Kernel 1: repack Wconv (f32 [64][33][300]) -> wsB bf16, fragment order.
// step id within (half, group): j*5+u, u indexes 32-elem sub-blocks of the 160-elem half.
__global__ __launch_bounds__(256) void prep_weights(const float* __restrict__ Wconv,
                                                    unsigned short* __restrict__ wsB) {
    int idx = blockIdx.x * 256 + threadIdx.x;      // < 430080
    int r    = idx & 7;
    int lane = (idx >> 3) & 63;
    int gs   = idx >> 9;                           // < 840
    int h    = gs / 420;
    int ww   = gs - h * 420;
    int g, t;
    if      (ww < 45)  { g = 0; t = ww;       }
    else if (ww < 130) { g = 1; t = ww - 45;  }
    else if (ww < 255) { g = 2; t = ww - 130; }
    else               { g = 3; t = ww - 255; }
    int j = t / 5, u = t - j * 5;
    int i  = g * 16 + (lane & 15);
    int ki = i / 2 + 2;
    int kk = (lane >> 4) * 8 + r;
    int e  = h * 160 + u * 32 + kk;
    float v = 0.f;
    if (e < EE && j < ki) v = Wconv[(i * KMAXW + j) * EE + e];
    wsB[idx] = f2bf(v);
}

#define MFMA(A, Bf, C) __builtin_amdgcn_mfma_f32_16x16x32_bf16((A), (Bf), (C), 0, 0, 0)

// One j-segment: groups g in [G0,4) are active (segment must lie in a G-pure j range).
// ar0 = At + m*LP + q*8 (lane's A base); bp = wsB half base + lane*8.
// B loaded first (<= 4 frags live), then one a-frag streams through its MFMAs.
template<int G0>
__device__ __forceinline__ void seg(const unsigned short* __restrict__ ar0,
                                    int jlo, int jhi,
                                    const unsigned short* __restrict__ bp,
                                    f32x4 acc[6][4]) {
    constexpr int GBASE[4] = {0, 45, 130, 255};
    #pragma unroll 1
    for (int j = jlo; j < jhi; ++j) {
        const unsigned short* ar = ar0 + j * LP;
        const unsigned short* br = bp + j * 5 * 512;
        #pragma unroll
        for (int u = 0; u < 5; ++u) {
            bf16x8 bf[4];
            #pragma unroll
            for (int g = G0; g < 4; ++g)
                bf[g] = *(const bf16x8*)(br + (GBASE[g] + u) * 512);
            #pragma unroll
            for (int t = 0; t < 6; ++t) {
                bf16x8 a = *(const bf16x8*)(ar + t * (16 * LP) + u * 32);
                #pragma unroll
                for (int g = G0; g < 4; ++g)
                    acc[t][g] = MFMA(a, bf[g], acc[t][g]);
            }
        }
    }
}

// ---- Kernel 2: fused gather + GEMM + cross-wave reduce + tanh + masked max.
__global__ __launch_bounds__(256, 2) void conv_fused(const int* __restrict__ x,
                                                     const float* __restrict__ emb,
                                                     const unsigned short* __restrict__ wsB,
                                                     const float* __restrict__ bconv,
                                                     float* __restrict__ wsF) {
    __shared__ __align__(16) unsigned short At[128 * LP];   // 42 KB

    int b     = blockIdx.x / 6;
    int slice = blockIdx.x - b * 6;
    int t0    = slice * 96;

    int lane = threadIdx.x & 63;
    int w    = threadIdx.x >> 6;
    int m = lane & 15, q = lane >> 4;

    f32x4 acc[6][4] = {};

    const unsigned short* ar0 = At + m * LP + q * 8;

    for (int eh = 0; eh < 2; ++eh) {
        if (eh) __syncthreads();       // all reads of previous half complete

        // Stage 128 half-rows (96 + 32 halo), f32 -> bf16, zero-padded.
        #pragma unroll
        for (int it = 0; it < 10; ++it) {
            int idx = threadIdx.x + it * 256;      // < 2560
            int rr = idx / 20, c = idx - rr * 20;
            int srow = t0 + rr;
            bf16x8 v = {0, 0, 0, 0, 0, 0, 0, 0};
            if (srow < SS) {
                int tok = x[b * SS + srow];
                const float* ep = emb + (long)tok * EE + eh * 160 + c * 8;
                if (eh == 0 || c < 17) {
                    float4 f0 = ((const float4*)ep)[0];
                    float4 f1 = ((const float4*)ep)[1];
                    v[0] = f2bf(f0.x); v[1] = f2bf(f0.y); v[2] = f2bf(f0.z); v[3] = f2bf(f0.w);
                    v[4] = f2bf(f1.x); v[5] = f2bf(f1.y); v[6] = f2bf(f1.z); v[7] = f2bf(f1.w);
                } else if (c == 17) {  // elems 296..299 valid
                    float4 f0 = ((const float4*)ep)[0];
                    v[0] = f2bf(f0.x); v[1] = f2bf(f0.y); v[2] = f2bf(f0.z); v[3] = f2bf(f0.w);
                }
            }
            *(bf16x8*)&At[rr * LP + c * 8] = v;
        }
        __syncthreads();

        const unsigned short* bp = wsB + eh * HALFSZ + lane * 8;
        // j-regions by active-group count: [0,9):4g, [9,17):3g, [17,25):2g, [25,33):1g.
        // Per-wave assignment balances MFMA exactly (630/wave/half) since same-id
        // waves of co-resident blocks share a SIMD pipe.
        if (w == 0) {
            seg<0>(ar0, 0, 3,  bp, acc); seg<1>(ar0, 9, 12, bp, acc);
        } else if (w == 1) {
            seg<0>(ar0, 3, 6,  bp, acc); seg<1>(ar0, 12, 15, bp, acc);
        } else if (w == 2) {
            seg<0>(ar0, 6, 9,  bp, acc); seg<1>(ar0, 15, 17, bp, acc);
            seg<3>(ar0, 25, 28, bp, acc);
        } else {
            seg<2>(ar0, 17, 25, bp, acc); seg<3>(ar0, 28, 33, bp, acc);
        }
    }

    // ---- Epilogue: sum j-partials across the 4 waves, then tanh + masked max.
    __syncthreads();                                  // done reading At
    float* red  = (float*)At;                         // [96][RP] = 26112 B
    float* red2 = red + 96 * RP;                      // [4][64]  = 1024 B

    #pragma unroll
    for (int it = 0; it < 7; ++it) {                  // zero 96*RP floats
        int idx = threadIdx.x + it * 256;
        if (idx < 96 * RP / 4) ((float4*)red)[idx] = float4{0.f, 0.f, 0.f, 0.f};
    }
    __syncthreads();

    // C/D map: col = m (filter in group), row = t*16 + q*4 + r.
    #pragma unroll
    for (int t = 0; t < 6; ++t)
        #pragma unroll
        for (int g = 0; g < 4; ++g)
            #pragma unroll
            for (int r = 0; r < 4; ++r)
                atomicAdd(&red[(t * 16 + q * 4 + r) * RP + g * 16 + m], acc[t][g][r]);
    __syncthreads();

    int f  = threadIdx.x & 63;                        // filter
    int rg = threadIdx.x >> 6;                        // row group (24 rows each)
    int ki = (f >> 1) + 2;
    int tmax = SS - ki;
    float bc = bconv[f];
    float mx = -3.0e38f;
    #pragma unroll 1
    for (int rr = 0; rr < 24; ++rr) {
        int row = rg * 24 + rr;
        int tb  = t0 + row;
        float v = tanhf(red[row * RP + f] + bc);
        if (tb <= tmax) mx = fmaxf(mx, v);
    }
    red2[rg * 64 + f] = mx;
    __syncthreads();
    if (threadIdx.x < 64) {
        float v = fmaxf(fmaxf(red2[f], red2[64 + f]),
                        fmaxf(red2[128 + f], red2[192 + f]));
        wsF[(b * HH + f) * 6 + slice] = v;
    }
}

// ---- Kernel 3: max over 6 partials, linear, sigmoid. 128 blocks x 64 thr.
__global__ __launch_bounds__(64) void final_linear(const float* __restrict__ wsF,
                                                   const float* __restrict__ Wlin,
                                                   const float* __restrict__ blin,
                                                   float* __restrict__ out) {
    int b = blockIdx.x;
    int i = threadIdx.x;
    const float* pp = wsF + (b * HH + i) * 6;
    float mx = pp[0];
    #pragma unroll
    for (int j = 1; j < 6; ++j) mx = fmaxf(mx, pp[j]);
    float v = mx * Wlin[i];
    #pragma unroll
    for (int off = 1; off < 64; off <<= 1) v += __shfl_xor(v, off);
    if (i == 0) out[b] = 1.0f / (1.0f + expf(-(v + blin[0])));
}

extern "C" void kernel_launch(void* const* d_in, const int* in_sizes, int n_in,
                              void* d_out, int out_size, void* d_ws, size_t ws_size,
                              hipStream_t stream) {
    const int*   x     = (const int*)d_in[0];
    const float* emb   = (const float*)d_in[1];
    const float* Wconv = (const float*)d_in[2];
    const float* bconv = (const float*)d_in[3];
    const float* Wlin  = (const float*)d_in[4];
    const float* blin  = (const float*)d_in[5];
    float* out = (float*)d_out;

    unsigned short* wsB = (unsigned short*)d_ws;
    float*          wsF = (float*)((char*)d_ws + (1u << 20));

    prep_weights<<<1680, 256, 0, stream>>>(Wconv, wsB);
    conv_fused<<<768, 256, 0, stream>>>(x, emb, wsB, bconv, wsF);
    final_linear<<<128, 64, 0, stream>>>(wsF, Wlin, blin, out);
}

// Round 3
// 183.839 us; speedup vs baseline: 1.9642x; 1.9642x over previous
//
#include <hip/hip_runtime.h>

// TextCNN: B=128, S=512, E=300, H=64, k_i = i/2+2 in [2,33].
// Virtual-im2col bf16 MFMA GEMM, fused gather, E-split LDS staging.
//   Grid: 128 b x 6 t-slices (96 rows each) = 768 blocks = 3/CU resident.
//   Block: 4 waves = 2-way M-split x 2-way j(K)-split. Wave (p,jh) owns
//   3 M-tiles (48 rows) x ALL active filter groups for its j-range:
//   A-frag LDS-read once per (j,u) per 16-row tile (1980 b128/block, was 3480
//   in the (p,h2) layout); B-frag from global/L2 feeds 3 M-tiles.
//   j-ranges balanced to exactly 630 MFMA/wave/half (SG(j)=84 -> 42+42).
//   acc[3][4] = 48 VGPRs (r1/r2's acc[6][4]=96 spilled: VGPR 84/128,
//   WRITE_SIZE 202/53 MB scratch traffic -- 48 is in the proven-safe range).
//   Epilogue: 2-phase jh-partial reduce in LDS (store then add, no atomics,
//   no zero-init), tanh + masked max.
//   LDS: 128 rows x 168-elem half-rows = 42 KB -> 3 blocks/CU.
// ws layout: [0, 860KB) wsB bf16 | [1MB, +192KB) wsF f32 (128*64*6).

#define SS     512
#define EE     300
#define HH     64
#define KMAXW  33
#define LP     168          // LDS half-row pitch in elems (336 B)
#define HALFSZ 215040       // wsB elems per E-half (420 steps * 512)
#define RP     68           // epilogue reduce pitch (floats)

typedef __attribute__((ext_vector_type(8))) short bf16x8;
typedef __attribute__((ext_vector_type(4))) float f32x4;

__device__ __forceinline__ unsigned short f2bf(float f) {
    unsigned u = __float_as_uint(f);
    unsigned r = ((u >> 16) & 1u) + 0x7FFFu;   // round-to-nearest-even
    return (unsigned short)((u + r) >> 16);
}

// ---- Kernel 1: repack Wconv (f32 [64][33][300]) -> wsB bf16, fragment order.
// step id within (half, group): j*5+u, u indexes 32-elem sub-blocks of the 160-elem half.
__global__ __launch_bounds__(256) void prep_weights(const float* __restrict__ Wconv,
                                                    unsigned short* __restrict__ wsB) {
    int idx = blockIdx.x * 256 + threadIdx.x;      // < 430080
    int r    = idx & 7;
    int lane = (idx >> 3) & 63;
    int gs   = idx >> 9;                           // < 840
    int h    = gs / 420;
    int ww   = gs - h * 420;
    int g, t;
    if      (ww < 45)  { g = 0; t = ww;       }
    else if (ww < 130) { g = 1; t = ww - 45;  }
    else if (ww < 255) { g = 2; t = ww - 130; }
    else               { g = 3; t = ww - 255; }
    int j = t / 5, u = t - j * 5;
    int i  = g * 16 + (lane & 15);
    int ki = i / 2 + 2;
    int kk = (lane >> 4) * 8 + r;
    int e  = h * 160 + u * 32 + kk;
    float v = 0.f;
    if (e < EE && j < ki) v = Wconv[(i * KMAXW + j) * EE + e];
    wsB[idx] = f2bf(v);
}

#define MFMA(A, Bf, C) __builtin_amdgcn_mfma_f32_16x16x32_bf16((A), (Bf), (C), 0, 0, 0)

// One j-segment: groups g in [G0,4) are active (segment must lie in a G-pure j range).
// ar0 = At + (p*48+m)*LP + q*8 (lane's A base); bp = wsB half base + lane*8.
// B loaded first (<= 4 frags live), then one a-frag streams through its MFMAs.
template<int G0>
__device__ __forceinline__ void seg(const unsigned short* __restrict__ ar0,
                                    int jlo, int jhi,
                                    const unsigned short* __restrict__ bp,
                                    f32x4 acc[3][4]) {
    constexpr int GBASE[4] = {0, 45, 130, 255};
    #pragma unroll 1
    for (int j = jlo; j < jhi; ++j) {
        const unsigned short* ar = ar0 + j * LP;
        const unsigned short* br = bp + j * 5 * 512;
        #pragma unroll
        for (int u = 0; u < 5; ++u) {
            bf16x8 bf[4];
            #pragma unroll
            for (int g = G0; g < 4; ++g)
                bf[g] = *(const bf16x8*)(br + (GBASE[g] + u) * 512);
            #pragma unroll
            for (int t = 0; t < 3; ++t) {
                bf16x8 a = *(const bf16x8*)(ar + t * (16 * LP) + u * 32);
                #pragma unroll
                for (int g = G0; g < 4; ++g)
                    acc[t][g] = MFMA(a, bf[g], acc[t][g]);
            }
        }
    }
}

// ---- Kernel 2: fused gather + GEMM + cross-wave reduce + tanh + masked max.
__global__ __launch_bounds__(256, 3) void conv_fused(const int* __restrict__ x,
                                                     const float* __restrict__ emb,
                                                     const unsigned short* __restrict__ wsB,
                                                     const float* __restrict__ bconv,
                                                     float* __restrict__ wsF) {
    __shared__ __align__(16) unsigned short At[128 * LP];   // 42 KB

    int b     = blockIdx.x / 6;
    int slice = blockIdx.x - b * 6;
    int t0    = slice * 96;

    int lane = threadIdx.x & 63;
    int w    = threadIdx.x >> 6;
    int p    = w >> 1;                 // M-half: 3 tiles of 16 rows
    int jh   = w & 1;                  // j-range half
    int m = lane & 15, q = lane >> 4;

    f32x4 acc[3][4] = {};

    const unsigned short* ar0 = At + (p * 48 + m) * LP + q * 8;

    for (int eh = 0; eh < 2; ++eh) {
        if (eh) __syncthreads();       // all reads of previous half complete

        // Stage 128 half-rows (96 + 32 halo), f32 -> bf16, zero-padded.
        #pragma unroll
        for (int it = 0; it < 10; ++it) {
            int idx = threadIdx.x + it * 256;      // < 2560
            int rr = idx / 20, c = idx - rr * 20;
            int srow = t0 + rr;
            bf16x8 v = {0, 0, 0, 0, 0, 0, 0, 0};
            if (srow < SS) {
                int tok = x[b * SS + srow];
                const float* ep = emb + (long)tok * EE + eh * 160 + c * 8;
                if (eh == 0 || c < 17) {
                    float4 f0 = ((const float4*)ep)[0];
                    float4 f1 = ((const float4*)ep)[1];
                    v[0] = f2bf(f0.x); v[1] = f2bf(f0.y); v[2] = f2bf(f0.z); v[3] = f2bf(f0.w);
                    v[4] = f2bf(f1.x); v[5] = f2bf(f1.y); v[6] = f2bf(f1.z); v[7] = f2bf(f1.w);
                } else if (c == 17) {  // elems 296..299 valid
                    float4 f0 = ((const float4*)ep)[0];
                    v[0] = f2bf(f0.x); v[1] = f2bf(f0.y); v[2] = f2bf(f0.z); v[3] = f2bf(f0.w);
                }
            }
            *(bf16x8*)&At[rr * LP + c * 8] = v;
        }
        __syncthreads();

        const unsigned short* bp = wsB + eh * HALFSZ + lane * 8;
        // j-regions by active-group count: [0,9):4g, [9,17):3g, [17,25):2g, [25,33):1g.
        // jh=0: [0,9)+[25,31) = 36+6 = 42 units; jh=1: [9,25)+[31,33) = 40+2 = 42.
        // (1 unit = 5u x 3t = 15 MFMA) -> 630 MFMA/wave/half, exact SIMD balance.
        if (jh == 0) {
            seg<0>(ar0, 0, 9,  bp, acc);
            seg<3>(ar0, 25, 31, bp, acc);
        } else {
            seg<1>(ar0, 9, 17, bp, acc);
            seg<2>(ar0, 17, 25, bp, acc);
            seg<3>(ar0, 31, 33, bp, acc);
        }
    }

    // ---- Epilogue: 2-phase jh-partial reduce in LDS, then tanh + masked max.
    __syncthreads();                                  // done reading At
    float* red  = (float*)At;                         // [96][RP] = 26112 B
    float* red2 = red + 96 * RP;                      // [4][64]  = 1024 B

    // C/D map: col = m (filter in group), row = p*48 + t*16 + q*4 + r.
    if (jh == 0) {
        #pragma unroll
        for (int t = 0; t < 3; ++t)
            #pragma unroll
            for (int g = 0; g < 4; ++g)
                #pragma unroll
                for (int r = 0; r < 4; ++r)
                    red[(p * 48 + t * 16 + q * 4 + r) * RP + g * 16 + m] = acc[t][g][r];
    }
    __syncthreads();
    if (jh == 1) {
        #pragma unroll
        for (int t = 0; t < 3; ++t)
            #pragma unroll
            for (int g = 0; g < 4; ++g)
                #pragma unroll
                for (int r = 0; r < 4; ++r)
                    red[(p * 48 + t * 16 + q * 4 + r) * RP + g * 16 + m] += acc[t][g][r];
    }
    __syncthreads();

    int f  = threadIdx.x & 63;                        // filter
    int rg = threadIdx.x >> 6;                        // row group (24 rows each)
    int ki = (f >> 1) + 2;
    int tmax = SS - ki;
    float bc = bconv[f];
    float mx = -3.0e38f;
    #pragma unroll 1
    for (int rr = 0; rr < 24; ++rr) {
        int row = rg * 24 + rr;
        int tb  = t0 + row;
        float v = tanhf(red[row * RP + f] + bc);
        if (tb <= tmax) mx = fmaxf(mx, v);
    }
    red2[rg * 64 + f] = mx;
    __syncthreads();
    if (threadIdx.x < 64) {
        float v = fmaxf(fmaxf(red2[f], red2[64 + f]),
                        fmaxf(red2[128 + f], red2[192 + f]));
        wsF[(b * HH + f) * 6 + slice] = v;
    }
}

// ---- Kernel 3: max over 6 partials, linear, sigmoid. 128 blocks x 64 thr.
__global__ __launch_bounds__(64) void final_linear(const float* __restrict__ wsF,
                                                   const float* __restrict__ Wlin,
                                                   const float* __restrict__ blin,
                                                   float* __restrict__ out) {
    int b = blockIdx.x;
    int i = threadIdx.x;
    const float* pp = wsF + (b * HH + i) * 6;
    float mx = pp[0];
    #pragma unroll
    for (int j = 1; j < 6; ++j) mx = fmaxf(mx, pp[j]);
    float v = mx * Wlin[i];
    #pragma unroll
    for (int off = 1; off < 64; off <<= 1) v += __shfl_xor(v, off);
    if (i == 0) out[b] = 1.0f / (1.0f + expf(-(v + blin[0])));
}

extern "C" void kernel_launch(void* const* d_in, const int* in_sizes, int n_in,
                              void* d_out, int out_size, void* d_ws, size_t ws_size,
                              hipStream_t stream) {
    const int*   x     = (const int*)d_in[0];
    const float* emb   = (const float*)d_in[1];
    const float* Wconv = (const float*)d_in[2];
    const float* bconv = (const float*)d_in[3];
    const float* Wlin  = (const float*)d_in[4];
    const float* blin  = (const float*)d_in[5];
    float* out = (float*)d_out;

    unsigned short* wsB = (unsigned short*)d_ws;
    float*          wsF = (float*)((char*)d_ws + (1u << 20));

    prep_weights<<<1680, 256, 0, stream>>>(Wconv, wsB);
    conv_fused<<<768, 256, 0, stream>>>(x, emb, wsB, bconv, wsF);
    final_linear<<<128, 64, 0, stream>>>(wsF, Wlin, blin, out);
}